// Round 4
// baseline (184.367 us; speedup 1.0000x reference)
//
#include <hip/hip_runtime.h>

#define DEVFN __device__ __forceinline__

constexpr int B = 4, S = 2048, H = 4, DH = 16, D = 64, F = 256;
constexpr int T = B * S;   // 8192 tokens

DEVFN float wave_sum(float v) {
#pragma unroll
    for (int mask = 32; mask >= 1; mask >>= 1)
        v += __shfl_xor(v, mask, 64);
    return v;
}

// ---------------------------------------------------------------- kernel 1
// QKV projection, 8 tokens per block (128 threads), grid 1024.
__global__ __launch_bounds__(128) void k_qkv(
    const float* __restrict__ x,
    const float* __restrict__ wq, const float* __restrict__ bq,
    const float* __restrict__ wk, const float* __restrict__ bk,
    const float* __restrict__ wv, const float* __restrict__ bv,
    float* __restrict__ Q, float* __restrict__ K, float* __restrict__ V)
{
    __shared__ float xs[8][64];
    int tid = threadIdx.x;
    int t0 = blockIdx.x * 8;
    ((float4*)xs)[tid] = ((const float4*)(x + t0 * D))[tid];
    __syncthreads();

    int j = tid & 63, g = tid >> 6;          // g in {0,1}
    int h = j >> 4, k = j & 15;
    int wbase = h * (D * DH) + k;

    float qa[4], ka[4], va[4];
#pragma unroll
    for (int i = 0; i < 4; ++i) { qa[i] = bq[j]; ka[i] = bk[j]; va[i] = bv[j]; }

#pragma unroll 8
    for (int d = 0; d < D; ++d) {
        float wqv = wq[wbase + d * DH];
        float wkv = wk[wbase + d * DH];
        float wvv = wv[wbase + d * DH];
#pragma unroll
        for (int i = 0; i < 4; ++i) {
            float xd = xs[g * 4 + i][d];
            qa[i] = fmaf(xd, wqv, qa[i]);
            ka[i] = fmaf(xd, wkv, ka[i]);
            va[i] = fmaf(xd, wvv, va[i]);
        }
    }
#pragma unroll
    for (int i = 0; i < 4; ++i) {
        int t = t0 + g * 4 + i;
        int b = t >> 11, s = t & (S - 1);
        int off = ((b * H + h) * S + s) * DH + k;
        Q[off] = qa[i] * 0.25f;   // fold 1/sqrt(16)
        K[off] = ka[i];
        V[off] = va[i];
    }
}

// ---------------------------------------------------------------- kernel 2a
// Causal flash attention, split-K partial pass.
// Block z: rblk = 31-(z>>6) (longest first), pair = (z>>2)&15, ks = z&3.
// 64 rows (lane-owned), keys [ks*nk4,(ks+1)*nk4) split over 4 waves.
// Partial {m,sum,acc[16]} per row -> P[z][18][64].
__global__ __launch_bounds__(256) void k_attn_part(
    const float* __restrict__ Q, const float* __restrict__ K,
    const float* __restrict__ V, float* __restrict__ P)
{
    __shared__ float part[3][64][19];

    int tid = threadIdx.x;
    int lane = tid & 63;
    int w = tid >> 6;                        // 0..3

    int z = blockIdx.x;
    int rblk = 31 - (z >> 6);
    int pair = (z >> 2) & 15;
    int ks   = z & 3;

    int rbase = rblk * 64;
    int row = rbase + lane;
    int nk4 = 16 * (rblk + 1);
    int kbeg = ks * nk4, kend = kbeg + nk4;

    const float4* q4 = (const float4*)(Q + (pair * S + row) * DH);
    float4 q0 = q4[0], q1 = q4[1], q2 = q4[2], q3 = q4[3];
    const float4* K4 = (const float4*)(K + pair * S * DH);
    const float4* V4 = (const float4*)(V + pair * S * DH);

    float m = -1e30f, sum = 0.f;
    float acc[16];
#pragma unroll
    for (int j = 0; j < 16; ++j) acc[j] = 0.f;

    for (int k0 = kbeg + w * 8; k0 < kend; k0 += 32) {
        float s[8];
#pragma unroll
        for (int i = 0; i < 8; ++i) {
            int kk = k0 + i;
            float4 ka = K4[kk * 4 + 0], kb = K4[kk * 4 + 1];
            float4 kc = K4[kk * 4 + 2], kd = K4[kk * 4 + 3];
            float sd;
            sd  = q0.x * ka.x; sd = fmaf(q0.y, ka.y, sd); sd = fmaf(q0.z, ka.z, sd); sd = fmaf(q0.w, ka.w, sd);
            sd = fmaf(q1.x, kb.x, sd); sd = fmaf(q1.y, kb.y, sd); sd = fmaf(q1.z, kb.z, sd); sd = fmaf(q1.w, kb.w, sd);
            sd = fmaf(q2.x, kc.x, sd); sd = fmaf(q2.y, kc.y, sd); sd = fmaf(q2.z, kc.z, sd); sd = fmaf(q2.w, kc.w, sd);
            sd = fmaf(q3.x, kd.x, sd); sd = fmaf(q3.y, kd.y, sd); sd = fmaf(q3.z, kd.z, sd); sd = fmaf(q3.w, kd.w, sd);
            s[i] = (kk <= row) ? sd : -1e30f;
        }
        float mc = m;
#pragma unroll
        for (int i = 0; i < 8; ++i) mc = fmaxf(mc, s[i]);
        float scale = __expf(m - mc);
        m = mc;
        float p[8];
        float psum = 0.f;
#pragma unroll
        for (int i = 0; i < 8; ++i) { p[i] = __expf(s[i] - mc); psum += p[i]; }
        sum = fmaf(sum, scale, psum);
#pragma unroll
        for (int j = 0; j < 16; ++j) acc[j] *= scale;
#pragma unroll
        for (int i = 0; i < 8; ++i) {
            int kk = k0 + i;
            float4 va = V4[kk * 4 + 0], vb = V4[kk * 4 + 1];
            float4 vc = V4[kk * 4 + 2], vd = V4[kk * 4 + 3];
            float pi = p[i];
            acc[ 0] = fmaf(pi, va.x, acc[ 0]); acc[ 1] = fmaf(pi, va.y, acc[ 1]);
            acc[ 2] = fmaf(pi, va.z, acc[ 2]); acc[ 3] = fmaf(pi, va.w, acc[ 3]);
            acc[ 4] = fmaf(pi, vb.x, acc[ 4]); acc[ 5] = fmaf(pi, vb.y, acc[ 5]);
            acc[ 6] = fmaf(pi, vb.z, acc[ 6]); acc[ 7] = fmaf(pi, vb.w, acc[ 7]);
            acc[ 8] = fmaf(pi, vc.x, acc[ 8]); acc[ 9] = fmaf(pi, vc.y, acc[ 9]);
            acc[10] = fmaf(pi, vc.z, acc[10]); acc[11] = fmaf(pi, vc.w, acc[11]);
            acc[12] = fmaf(pi, vd.x, acc[12]); acc[13] = fmaf(pi, vd.y, acc[13]);
            acc[14] = fmaf(pi, vd.z, acc[14]); acc[15] = fmaf(pi, vd.w, acc[15]);
        }
    }

    if (w > 0) {
        float* pp = &part[w - 1][lane][0];
        pp[0] = m; pp[1] = sum;
#pragma unroll
        for (int j = 0; j < 16; ++j) pp[2 + j] = acc[j];
    }
    __syncthreads();
    if (w == 0) {
#pragma unroll
        for (int ww = 0; ww < 3; ++ww) {
            const float* qq = &part[ww][lane][0];
            float m2 = qq[0], s2 = qq[1];
            float M  = fmaxf(m, m2);
            float e1 = __expf(m - M), e2 = __expf(m2 - M);
            sum = sum * e1 + s2 * e2;
#pragma unroll
            for (int j = 0; j < 16; ++j)
                acc[j] = acc[j] * e1 + qq[2 + j] * e2;
            m = M;
        }
        float* pp = P + (size_t)z * (18 * 64);
        pp[0 * 64 + lane] = m;
        pp[1 * 64 + lane] = sum;
#pragma unroll
        for (int j = 0; j < 16; ++j) pp[(2 + j) * 64 + lane] = acc[j];
    }
}

// ---------------------------------------------------------------- kernel 2b
// Merge 4 split-K partials per row, normalize, write A (head-concat).
__global__ __launch_bounds__(256) void k_attn_merge(
    const float* __restrict__ P, float* __restrict__ A)
{
    __shared__ float part[3][64][19];
    int tid = threadIdx.x, lane = tid & 63, w = tid >> 6;
    int y = blockIdx.x;
    int pair = y >> 5, rblk = y & 31;
    int z = (((31 - rblk) << 6) | (pair << 2)) + w;

    const float* pp = P + (size_t)z * (18 * 64);
    float m = pp[0 * 64 + lane], sum = pp[1 * 64 + lane];
    float acc[16];
#pragma unroll
    for (int j = 0; j < 16; ++j) acc[j] = pp[(2 + j) * 64 + lane];

    if (w > 0) {
        float* sp = &part[w - 1][lane][0];
        sp[0] = m; sp[1] = sum;
#pragma unroll
        for (int j = 0; j < 16; ++j) sp[2 + j] = acc[j];
    }
    __syncthreads();
    if (w == 0) {
#pragma unroll
        for (int ww = 0; ww < 3; ++ww) {
            const float* qq = &part[ww][lane][0];
            float m2 = qq[0], s2 = qq[1];
            float M  = fmaxf(m, m2);
            float e1 = __expf(m - M), e2 = __expf(m2 - M);
            sum = sum * e1 + s2 * e2;
#pragma unroll
            for (int j = 0; j < 16; ++j)
                acc[j] = acc[j] * e1 + qq[2 + j] * e2;
            m = M;
        }
        float inv = 1.f / sum;
        int b = pair >> 2, h = pair & 3;
        int row = rblk * 64 + lane;
        float4* Ap = (float4*)(A + (b * S + row) * D + h * DH);
        float4 o0 = { acc[ 0] * inv, acc[ 1] * inv, acc[ 2] * inv, acc[ 3] * inv };
        float4 o1 = { acc[ 4] * inv, acc[ 5] * inv, acc[ 6] * inv, acc[ 7] * inv };
        float4 o2 = { acc[ 8] * inv, acc[ 9] * inv, acc[10] * inv, acc[11] * inv };
        float4 o3 = { acc[12] * inv, acc[13] * inv, acc[14] * inv, acc[15] * inv };
        Ap[0] = o0; Ap[1] = o1; Ap[2] = o2; Ap[3] = o3;
    }
}

// ---------------------------------------------------------------- kernel 3
// Out-projection + residual + LayerNorm1, 8 tokens per block (128 thr).
__global__ __launch_bounds__(128) void k_oproj(
    const float* __restrict__ A, const float* __restrict__ x,
    const float* __restrict__ wo, const float* __restrict__ bo,
    const float* __restrict__ g1, const float* __restrict__ bb1,
    float* __restrict__ R1)
{
    __shared__ float as[8][64];
    int tid = threadIdx.x;
    int t0 = blockIdx.x * 8;
    ((float4*)as)[tid] = ((const float4*)(A + t0 * D))[tid];
    __syncthreads();

    int j = tid & 63, g = tid >> 6;
    float o[4];
#pragma unroll
    for (int i = 0; i < 4; ++i)
        o[i] = bo[j] + x[(t0 + g * 4 + i) * D + j];

#pragma unroll 8
    for (int d = 0; d < D; ++d) {
        float wv = wo[d * D + j];
#pragma unroll
        for (int i = 0; i < 4; ++i)
            o[i] = fmaf(as[g * 4 + i][d], wv, o[i]);
    }
    float gj = g1[j], bj = bb1[j];
#pragma unroll
    for (int i = 0; i < 4; ++i) {
        float mu  = wave_sum(o[i]) * (1.f / 64.f);
        float dif = o[i] - mu;
        float var = wave_sum(dif * dif) * (1.f / 64.f);
        R1[(t0 + g * 4 + i) * D + j] = dif * rsqrtf(var + 1e-5f) * gj + bj;
    }
}

// ---------------------------------------------------------------- kernel 4
// FFN + residual + LayerNorm2, 16 tokens per block, 512 threads.
__global__ __launch_bounds__(512) void k_ffn(
    const float* __restrict__ R1,
    const float* __restrict__ w1, const float* __restrict__ b1,
    const float* __restrict__ w2, const float* __restrict__ b2,
    const float* __restrict__ g2, const float* __restrict__ bb2,
    float* __restrict__ out)
{
    __shared__ float xr[16][64];      // 4 KB
    __shared__ float hh[256][20];     // 20 KB, padded stride
    int tid = threadIdx.x;
    int t0 = blockIdx.x * 16;
    if (tid < 256)
        ((float4*)xr)[tid] = ((const float4*)(R1 + t0 * D))[tid];
    __syncthreads();

    // stage 1: thread (f, half) computes hidden f for 8 tokens
    int f = tid & 255, half = tid >> 8;
    float h[8];
#pragma unroll
    for (int t = 0; t < 8; ++t) h[t] = b1[f];
#pragma unroll 8
    for (int d = 0; d < D; ++d) {
        float wv = w1[d * F + f];
#pragma unroll
        for (int t = 0; t < 8; ++t)
            h[t] = fmaf(xr[half * 8 + t][d], wv, h[t]);
    }
#pragma unroll
    for (int t = 0; t < 8; t += 4) {
        float4 hv = { fmaxf(h[t], 0.f), fmaxf(h[t+1], 0.f),
                      fmaxf(h[t+2], 0.f), fmaxf(h[t+3], 0.f) };
        *(float4*)&hh[f][half * 8 + t] = hv;
    }
    __syncthreads();

    // stage 2: thread (j, g) computes output col j for tokens 2g, 2g+1
    int j = tid & 63, g = tid >> 6;          // g in 0..7
    float y0 = b2[j] + xr[2 * g + 0][j];
    float y1 = b2[j] + xr[2 * g + 1][j];
#pragma unroll 8
    for (int ff = 0; ff < F; ++ff) {
        float wv = w2[ff * D + j];
        float2 hv = *(const float2*)&hh[ff][2 * g];
        y0 = fmaf(hv.x, wv, y0);
        y1 = fmaf(hv.y, wv, y1);
    }
    float gj = g2[j], bj = bb2[j];
    {
        float mu  = wave_sum(y0) * (1.f / 64.f);
        float dif = y0 - mu;
        float var = wave_sum(dif * dif) * (1.f / 64.f);
        out[(t0 + 2 * g + 0) * D + j] = dif * rsqrtf(var + 1e-5f) * gj + bj;
    }
    {
        float mu  = wave_sum(y1) * (1.f / 64.f);
        float dif = y1 - mu;
        float var = wave_sum(dif * dif) * (1.f / 64.f);
        out[(t0 + 2 * g + 1) * D + j] = dif * rsqrtf(var + 1e-5f) * gj + bj;
    }
}

// ----------------------------------------------------------------
extern "C" void kernel_launch(void* const* d_in, const int* in_sizes, int n_in,
                              void* d_out, int out_size, void* d_ws, size_t ws_size,
                              hipStream_t stream)
{
    const float* x   = (const float*)d_in[0];
    const float* wq  = (const float*)d_in[1];
    const float* bq  = (const float*)d_in[2];
    const float* wk  = (const float*)d_in[3];
    const float* bk  = (const float*)d_in[4];
    const float* wv  = (const float*)d_in[5];
    const float* bv  = (const float*)d_in[6];
    const float* wo  = (const float*)d_in[7];
    const float* bo  = (const float*)d_in[8];
    const float* g1  = (const float*)d_in[9];
    const float* be1 = (const float*)d_in[10];
    const float* w1  = (const float*)d_in[11];
    const float* b1  = (const float*)d_in[12];
    const float* w2  = (const float*)d_in[13];
    const float* b2  = (const float*)d_in[14];
    const float* g2  = (const float*)d_in[15];
    const float* be2 = (const float*)d_in[16];

    float* ws = (float*)d_ws;
    float* Q  = ws;               // [16, 2048, 16]
    float* K  = Q + T * D;        // [16, 2048, 16]
    float* V  = K + T * D;        // [16, 2048, 16]
    float* A  = V + T * D;        // [B, S, 64]
    float* R1 = A + T * D;        // [B, S, 64]
    float* P  = R1 + T * D;       // [2048][18][64] split-K partials

    k_qkv       <<<T / 8, 128, 0, stream>>>(x, wq, bq, wk, bk, wv, bv, Q, K, V);
    k_attn_part <<<2048, 256, 0, stream>>>(Q, K, V, P);
    k_attn_merge<<<512, 256, 0, stream>>>(P, A);
    k_oproj     <<<T / 8, 128, 0, stream>>>(A, x, wo, bo, g1, be1, R1);
    k_ffn       <<<T / 16, 512, 0, stream>>>(R1, w1, b1, w2, b2, g2, be2, (float*)d_out);
}

// Round 5
// 104.154 us; speedup vs baseline: 1.7701x; 1.7701x over previous
//
#include <hip/hip_runtime.h>

#define DEVFN __device__ __forceinline__

constexpr int B = 4, S = 2048, H = 4, DH = 16, D = 64, F = 256;
constexpr int T = B * S;        // 8192 tokens
constexpr int PAIRS = B * H;    // 16
constexpr int CPP = 136;        // chunk-blocks per pair = sum_{rb=0..15}(rb+1)
constexpr int NZ = PAIRS * CPP; // 2176 attention partial blocks
constexpr int PSTRIDE = 1280;   // floats per partial: 128 m + 128 sum + 16x128 bf16

DEVFN float wave_sum(float v) {
#pragma unroll
    for (int mask = 32; mask >= 1; mask >>= 1)
        v += __shfl_xor(v, mask, 64);
    return v;
}

DEVFN float bf2f(unsigned short u) { return __uint_as_float((unsigned)u << 16); }
DEVFN unsigned short f2bf(float f) {
    unsigned b = __float_as_uint(f);
    return (unsigned short)((b + 0x8000u) >> 16);
}

// ---------------------------------------------------------------- kernel 1
// QKV projection, 8 tokens per block. Q fp32 (1/4 folded), K/V bf16.
__global__ __launch_bounds__(128) void k_qkv(
    const float* __restrict__ x,
    const float* __restrict__ wq, const float* __restrict__ bq,
    const float* __restrict__ wk, const float* __restrict__ bk,
    const float* __restrict__ wv, const float* __restrict__ bv,
    float* __restrict__ Q, unsigned short* __restrict__ Kb,
    unsigned short* __restrict__ Vb)
{
    __shared__ float xs[8][64];
    int tid = threadIdx.x;
    int t0 = blockIdx.x * 8;
    ((float4*)xs)[tid] = ((const float4*)(x + t0 * D))[tid];
    __syncthreads();

    int j = tid & 63, g = tid >> 6;
    int h = j >> 4, k = j & 15;
    int wbase = h * (D * DH) + k;

    float qa[4], ka[4], va[4];
#pragma unroll
    for (int i = 0; i < 4; ++i) { qa[i] = bq[j]; ka[i] = bk[j]; va[i] = bv[j]; }

#pragma unroll 8
    for (int d = 0; d < D; ++d) {
        float wqv = wq[wbase + d * DH];
        float wkv = wk[wbase + d * DH];
        float wvv = wv[wbase + d * DH];
#pragma unroll
        for (int i = 0; i < 4; ++i) {
            float xd = xs[g * 4 + i][d];
            qa[i] = fmaf(xd, wqv, qa[i]);
            ka[i] = fmaf(xd, wkv, ka[i]);
            va[i] = fmaf(xd, wvv, va[i]);
        }
    }
#pragma unroll
    for (int i = 0; i < 4; ++i) {
        int t = t0 + g * 4 + i;
        int b = t >> 11, s = t & (S - 1);
        int off = ((b * H + h) * S + s) * DH + k;
        Q[off]  = qa[i] * 0.25f;
        Kb[off] = f2bf(ka[i]);
        Vb[off] = f2bf(va[i]);
    }
}

// ---------------------------------------------------------------- kernel 2a
// Flash attention partial, equal-work blocks.
// Block z -> (pair, rb, c): 128 rows [rb*128, +128), 128 keys [c*128, +128),
// only chunks c<=rb exist. 2 waves split the keys (64 each), each lane owns
// 2 rows (lane, lane+64). K/V tiles staged bf16->f32 in LDS; per-key reads
// are wave-uniform ds_read_b128 broadcasts (conflict-free).
__global__ __launch_bounds__(128) void k_attn_part(
    const float* __restrict__ Q, const unsigned short* __restrict__ Kb,
    const unsigned short* __restrict__ Vb, float* __restrict__ P)
{
    union SH {
        float4 t[4][64][4];   // tiles: K(w0), K(w1), V(w0), V(w1)  16 KB
        struct { float m1[128], s1[128], a1[16][128]; } mg;
    };
    __shared__ SH sh;

    int tid = threadIdx.x, lane = tid & 63;
    int w = tid >> 6;

    int z = blockIdx.x;
    int pair = z / CPP;
    int t = z - pair * CPP;
    int rb = 0, cum = 0;
    while (cum + rb + 1 <= t) { cum += rb + 1; ++rb; }
    int c = t - cum;
    int rbase = rb * 128;
    int k0 = c * 128;

    // ---- stage K/V tiles (128 keys): bf16 global -> f32 LDS, all linear
    {
        const unsigned* kp = (const unsigned*)(Kb + (pair * S + k0) * DH);
        const unsigned* vp = (const unsigned*)(Vb + (pair * S + k0) * DH);
        float4* lds = (float4*)&sh.t[0][0][0];
#pragma unroll
        for (int i = 0; i < 4; ++i) {
            int f = tid + 128 * i;                 // float4 slot in K region
            unsigned u0 = kp[f * 2], u1 = kp[f * 2 + 1];
            float4 val;
            val.x = __uint_as_float(u0 << 16);
            val.y = __uint_as_float(u0 & 0xffff0000u);
            val.z = __uint_as_float(u1 << 16);
            val.w = __uint_as_float(u1 & 0xffff0000u);
            lds[f] = val;
        }
#pragma unroll
        for (int i = 0; i < 4; ++i) {
            int f = tid + 128 * i;
            unsigned u0 = vp[f * 2], u1 = vp[f * 2 + 1];
            float4 val;
            val.x = __uint_as_float(u0 << 16);
            val.y = __uint_as_float(u0 & 0xffff0000u);
            val.z = __uint_as_float(u1 << 16);
            val.w = __uint_as_float(u1 & 0xffff0000u);
            lds[512 + f] = val;
        }
    }
    __syncthreads();

    int r0 = rbase + lane, r1 = r0 + 64;
    const float4* q4a = (const float4*)(Q + (pair * S + r0) * DH);
    const float4* q4b = (const float4*)(Q + (pair * S + r1) * DH);
    float4 qa0 = q4a[0], qa1 = q4a[1], qa2 = q4a[2], qa3 = q4a[3];
    float4 qb0 = q4b[0], qb1 = q4b[1], qb2 = q4b[2], qb3 = q4b[3];

    const float4* KT = (const float4*)&sh.t[w][0][0];
    const float4* VT = (const float4*)&sh.t[2 + w][0][0];
    int kgbase = k0 + w * 64;

    float m0 = -1e30f, m1 = -1e30f, sum0 = 0.f, sum1 = 0.f;
    float acc0[16], acc1[16];
#pragma unroll
    for (int j = 0; j < 16; ++j) { acc0[j] = 0.f; acc1[j] = 0.f; }

    for (int cc = 0; cc < 64; cc += 8) {
        float s0[8], s1[8];
#pragma unroll
        for (int i = 0; i < 8; ++i) {
            int kl = cc + i;
            float4 ka = KT[kl * 4 + 0], kb = KT[kl * 4 + 1];
            float4 kc = KT[kl * 4 + 2], kd = KT[kl * 4 + 3];
            float d0, d1;
            d0  = qa0.x * ka.x; d0 = fmaf(qa0.y, ka.y, d0); d0 = fmaf(qa0.z, ka.z, d0); d0 = fmaf(qa0.w, ka.w, d0);
            d0 = fmaf(qa1.x, kb.x, d0); d0 = fmaf(qa1.y, kb.y, d0); d0 = fmaf(qa1.z, kb.z, d0); d0 = fmaf(qa1.w, kb.w, d0);
            d0 = fmaf(qa2.x, kc.x, d0); d0 = fmaf(qa2.y, kc.y, d0); d0 = fmaf(qa2.z, kc.z, d0); d0 = fmaf(qa2.w, kc.w, d0);
            d0 = fmaf(qa3.x, kd.x, d0); d0 = fmaf(qa3.y, kd.y, d0); d0 = fmaf(qa3.z, kd.z, d0); d0 = fmaf(qa3.w, kd.w, d0);
            d1  = qb0.x * ka.x; d1 = fmaf(qb0.y, ka.y, d1); d1 = fmaf(qb0.z, ka.z, d1); d1 = fmaf(qb0.w, ka.w, d1);
            d1 = fmaf(qb1.x, kb.x, d1); d1 = fmaf(qb1.y, kb.y, d1); d1 = fmaf(qb1.z, kb.z, d1); d1 = fmaf(qb1.w, kb.w, d1);
            d1 = fmaf(qb2.x, kc.x, d1); d1 = fmaf(qb2.y, kc.y, d1); d1 = fmaf(qb2.z, kc.z, d1); d1 = fmaf(qb2.w, kc.w, d1);
            d1 = fmaf(qb3.x, kd.x, d1); d1 = fmaf(qb3.y, kd.y, d1); d1 = fmaf(qb3.z, kd.z, d1); d1 = fmaf(qb3.w, kd.w, d1);
            int kg = kgbase + kl;
            s0[i] = (kg <= r0) ? d0 : -1e30f;
            s1[i] = (kg <= r1) ? d1 : -1e30f;
        }
        float mc0 = m0, mc1 = m1;
#pragma unroll
        for (int i = 0; i < 8; ++i) { mc0 = fmaxf(mc0, s0[i]); mc1 = fmaxf(mc1, s1[i]); }
        float sc0 = __expf(m0 - mc0), sc1 = __expf(m1 - mc1);
        m0 = mc0; m1 = mc1;
        float ps0 = 0.f, ps1 = 0.f;
#pragma unroll
        for (int i = 0; i < 8; ++i) {
            s0[i] = __expf(s0[i] - mc0); ps0 += s0[i];
            s1[i] = __expf(s1[i] - mc1); ps1 += s1[i];
        }
        sum0 = fmaf(sum0, sc0, ps0);
        sum1 = fmaf(sum1, sc1, ps1);
#pragma unroll
        for (int j = 0; j < 16; ++j) { acc0[j] *= sc0; acc1[j] *= sc1; }
#pragma unroll
        for (int i = 0; i < 8; ++i) {
            int kl = cc + i;
            float4 va = VT[kl * 4 + 0], vb = VT[kl * 4 + 1];
            float4 vc = VT[kl * 4 + 2], vd = VT[kl * 4 + 3];
            float p0 = s0[i], p1 = s1[i];
            acc0[ 0] = fmaf(p0, va.x, acc0[ 0]); acc0[ 1] = fmaf(p0, va.y, acc0[ 1]);
            acc0[ 2] = fmaf(p0, va.z, acc0[ 2]); acc0[ 3] = fmaf(p0, va.w, acc0[ 3]);
            acc0[ 4] = fmaf(p0, vb.x, acc0[ 4]); acc0[ 5] = fmaf(p0, vb.y, acc0[ 5]);
            acc0[ 6] = fmaf(p0, vb.z, acc0[ 6]); acc0[ 7] = fmaf(p0, vb.w, acc0[ 7]);
            acc0[ 8] = fmaf(p0, vc.x, acc0[ 8]); acc0[ 9] = fmaf(p0, vc.y, acc0[ 9]);
            acc0[10] = fmaf(p0, vc.z, acc0[10]); acc0[11] = fmaf(p0, vc.w, acc0[11]);
            acc0[12] = fmaf(p0, vd.x, acc0[12]); acc0[13] = fmaf(p0, vd.y, acc0[13]);
            acc0[14] = fmaf(p0, vd.z, acc0[14]); acc0[15] = fmaf(p0, vd.w, acc0[15]);
            acc1[ 0] = fmaf(p1, va.x, acc1[ 0]); acc1[ 1] = fmaf(p1, va.y, acc1[ 1]);
            acc1[ 2] = fmaf(p1, va.z, acc1[ 2]); acc1[ 3] = fmaf(p1, va.w, acc1[ 3]);
            acc1[ 4] = fmaf(p1, vb.x, acc1[ 4]); acc1[ 5] = fmaf(p1, vb.y, acc1[ 5]);
            acc1[ 6] = fmaf(p1, vb.z, acc1[ 6]); acc1[ 7] = fmaf(p1, vb.w, acc1[ 7]);
            acc1[ 8] = fmaf(p1, vc.x, acc1[ 8]); acc1[ 9] = fmaf(p1, vc.y, acc1[ 9]);
            acc1[10] = fmaf(p1, vc.z, acc1[10]); acc1[11] = fmaf(p1, vc.w, acc1[11]);
            acc1[12] = fmaf(p1, vd.x, acc1[12]); acc1[13] = fmaf(p1, vd.y, acc1[13]);
            acc1[14] = fmaf(p1, vd.z, acc1[14]); acc1[15] = fmaf(p1, vd.w, acc1[15]);
        }
    }

    // ---- in-block merge of the 2 key-split waves, write partial
    __syncthreads();
    if (w == 1) {
        sh.mg.m1[lane] = m0;      sh.mg.m1[64 + lane] = m1;
        sh.mg.s1[lane] = sum0;    sh.mg.s1[64 + lane] = sum1;
#pragma unroll
        for (int j = 0; j < 16; ++j) {
            sh.mg.a1[j][lane] = acc0[j];
            sh.mg.a1[j][64 + lane] = acc1[j];
        }
    }
    __syncthreads();
    if (w == 0) {
        float* base = P + (size_t)z * PSTRIDE;
        unsigned short* pa = (unsigned short*)(base + 256);
        {
            float m2 = sh.mg.m1[lane], s2 = sh.mg.s1[lane];
            float M = fmaxf(m0, m2);
            float e1 = __expf(m0 - M), e2 = __expf(m2 - M);
            float sm = sum0 * e1 + s2 * e2;
            base[lane] = M; base[128 + lane] = sm;
#pragma unroll
            for (int j = 0; j < 16; ++j)
                pa[j * 128 + lane] = f2bf(acc0[j] * e1 + sh.mg.a1[j][lane] * e2);
        }
        {
            float m2 = sh.mg.m1[64 + lane], s2 = sh.mg.s1[64 + lane];
            float M = fmaxf(m1, m2);
            float e1 = __expf(m1 - M), e2 = __expf(m2 - M);
            float sm = sum1 * e1 + s2 * e2;
            base[64 + lane] = M; base[128 + 64 + lane] = sm;
#pragma unroll
            for (int j = 0; j < 16; ++j)
                pa[j * 128 + 64 + lane] = f2bf(acc1[j] * e1 + sh.mg.a1[j][64 + lane] * e2);
        }
    }
}

// ---------------------------------------------------------------- kernel 2b
// Merge the (rb+1) key-chunk partials per 128-row group, write A.
__global__ __launch_bounds__(128) void k_attn_merge(
    const float* __restrict__ P, float* __restrict__ A)
{
    int j = threadIdx.x;                       // row within group
    int y = blockIdx.x;
    int pair = y >> 4, rb = y & 15;
    int row = rb * 128 + j;
    size_t z0 = (size_t)pair * CPP + rb * (rb + 1) / 2;

    const float* base = P + z0 * PSTRIDE;
    float M = base[j], Sm = base[128 + j];
    float acc[16];
    const unsigned short* pa = (const unsigned short*)(base + 256);
#pragma unroll
    for (int d = 0; d < 16; ++d) acc[d] = bf2f(pa[d * 128 + j]);

    for (int c = 1; c <= rb; ++c) {
        base += PSTRIDE;
        pa = (const unsigned short*)(base + 256);
        float m2 = base[j], s2 = base[128 + j];
        float Mn = fmaxf(M, m2);
        float e1 = __expf(M - Mn), e2 = __expf(m2 - Mn);
        Sm = Sm * e1 + s2 * e2;
#pragma unroll
        for (int d = 0; d < 16; ++d)
            acc[d] = acc[d] * e1 + bf2f(pa[d * 128 + j]) * e2;
        M = Mn;
    }
    float inv = 1.f / Sm;
    int b = pair >> 2, h = pair & 3;
    float4* Ap = (float4*)(A + ((size_t)(b * S + row)) * D + h * DH);
    float4 o0 = { acc[ 0] * inv, acc[ 1] * inv, acc[ 2] * inv, acc[ 3] * inv };
    float4 o1 = { acc[ 4] * inv, acc[ 5] * inv, acc[ 6] * inv, acc[ 7] * inv };
    float4 o2 = { acc[ 8] * inv, acc[ 9] * inv, acc[10] * inv, acc[11] * inv };
    float4 o3 = { acc[12] * inv, acc[13] * inv, acc[14] * inv, acc[15] * inv };
    Ap[0] = o0; Ap[1] = o1; Ap[2] = o2; Ap[3] = o3;
}

// ---------------------------------------------------------------- kernel 3
// Out-projection + residual + LayerNorm1, 8 tokens per block.
__global__ __launch_bounds__(128) void k_oproj(
    const float* __restrict__ A, const float* __restrict__ x,
    const float* __restrict__ wo, const float* __restrict__ bo,
    const float* __restrict__ g1, const float* __restrict__ bb1,
    float* __restrict__ R1)
{
    __shared__ float as[8][64];
    int tid = threadIdx.x;
    int t0 = blockIdx.x * 8;
    ((float4*)as)[tid] = ((const float4*)(A + t0 * D))[tid];
    __syncthreads();

    int j = tid & 63, g = tid >> 6;
    float o[4];
#pragma unroll
    for (int i = 0; i < 4; ++i)
        o[i] = bo[j] + x[(t0 + g * 4 + i) * D + j];

#pragma unroll 8
    for (int d = 0; d < D; ++d) {
        float wv = wo[d * D + j];
#pragma unroll
        for (int i = 0; i < 4; ++i)
            o[i] = fmaf(as[g * 4 + i][d], wv, o[i]);
    }
    float gj = g1[j], bj = bb1[j];
#pragma unroll
    for (int i = 0; i < 4; ++i) {
        float mu  = wave_sum(o[i]) * (1.f / 64.f);
        float dif = o[i] - mu;
        float var = wave_sum(dif * dif) * (1.f / 64.f);
        R1[(t0 + g * 4 + i) * D + j] = dif * rsqrtf(var + 1e-5f) * gj + bj;
    }
}

// ---------------------------------------------------------------- kernel 4
// FFN + residual + LayerNorm2, 16 tokens per block, 512 threads.
__global__ __launch_bounds__(512) void k_ffn(
    const float* __restrict__ R1,
    const float* __restrict__ w1, const float* __restrict__ b1,
    const float* __restrict__ w2, const float* __restrict__ b2,
    const float* __restrict__ g2, const float* __restrict__ bb2,
    float* __restrict__ out)
{
    __shared__ float xr[16][64];
    __shared__ float hh[256][20];
    int tid = threadIdx.x;
    int t0 = blockIdx.x * 16;
    if (tid < 256)
        ((float4*)xr)[tid] = ((const float4*)(R1 + t0 * D))[tid];
    __syncthreads();

    int f = tid & 255, half = tid >> 8;
    float h[8];
#pragma unroll
    for (int t = 0; t < 8; ++t) h[t] = b1[f];
#pragma unroll 8
    for (int d = 0; d < D; ++d) {
        float wv = w1[d * F + f];
#pragma unroll
        for (int t = 0; t < 8; ++t)
            h[t] = fmaf(xr[half * 8 + t][d], wv, h[t]);
    }
#pragma unroll
    for (int t = 0; t < 8; t += 4) {
        float4 hv = { fmaxf(h[t], 0.f), fmaxf(h[t+1], 0.f),
                      fmaxf(h[t+2], 0.f), fmaxf(h[t+3], 0.f) };
        *(float4*)&hh[f][half * 8 + t] = hv;
    }
    __syncthreads();

    int j = tid & 63, g = tid >> 6;
    float y0 = b2[j] + xr[2 * g + 0][j];
    float y1 = b2[j] + xr[2 * g + 1][j];
#pragma unroll 8
    for (int ff = 0; ff < F; ++ff) {
        float wv = w2[ff * D + j];
        float2 hv = *(const float2*)&hh[ff][2 * g];
        y0 = fmaf(hv.x, wv, y0);
        y1 = fmaf(hv.y, wv, y1);
    }
    float gj = g2[j], bj = bb2[j];
    {
        float mu  = wave_sum(y0) * (1.f / 64.f);
        float dif = y0 - mu;
        float var = wave_sum(dif * dif) * (1.f / 64.f);
        out[(t0 + 2 * g + 0) * D + j] = dif * rsqrtf(var + 1e-5f) * gj + bj;
    }
    {
        float mu  = wave_sum(y1) * (1.f / 64.f);
        float dif = y1 - mu;
        float var = wave_sum(dif * dif) * (1.f / 64.f);
        out[(t0 + 2 * g + 1) * D + j] = dif * rsqrtf(var + 1e-5f) * gj + bj;
    }
}

// ----------------------------------------------------------------
extern "C" void kernel_launch(void* const* d_in, const int* in_sizes, int n_in,
                              void* d_out, int out_size, void* d_ws, size_t ws_size,
                              hipStream_t stream)
{
    const float* x   = (const float*)d_in[0];
    const float* wq  = (const float*)d_in[1];
    const float* bq  = (const float*)d_in[2];
    const float* wk  = (const float*)d_in[3];
    const float* bk  = (const float*)d_in[4];
    const float* wv  = (const float*)d_in[5];
    const float* bv  = (const float*)d_in[6];
    const float* wo  = (const float*)d_in[7];
    const float* bo  = (const float*)d_in[8];
    const float* g1  = (const float*)d_in[9];
    const float* be1 = (const float*)d_in[10];
    const float* w1  = (const float*)d_in[11];
    const float* b1  = (const float*)d_in[12];
    const float* w2  = (const float*)d_in[13];
    const float* b2  = (const float*)d_in[14];
    const float* g2  = (const float*)d_in[15];
    const float* be2 = (const float*)d_in[16];

    char* base = (char*)d_ws;
    float*          Q  = (float*)base;                            // 2 MB
    unsigned short* Kb = (unsigned short*)(base + (2u << 20));    // 1 MB
    unsigned short* Vb = (unsigned short*)(base + (3u << 20));    // 1 MB
    float*          A  = (float*)(base + (4u << 20));             // 2 MB
    float*          R1 = (float*)(base + (6u << 20));             // 2 MB
    float*          P  = (float*)(base + (8u << 20));             // 11.14 MB

    k_qkv       <<<T / 8, 128, 0, stream>>>(x, wq, bq, wk, bk, wv, bv, Q, Kb, Vb);
    k_attn_part <<<NZ, 128, 0, stream>>>(Q, Kb, Vb, P);
    k_attn_merge<<<PAIRS * 16, 128, 0, stream>>>(P, A);
    k_oproj     <<<T / 8, 128, 0, stream>>>(A, x, wo, bo, g1, be1, R1);
    k_ffn       <<<T / 16, 512, 0, stream>>>(R1, w1, b1, w2, b2, g2, be2, (float*)d_out);
}

// Round 6
// 76.031 us; speedup vs baseline: 2.4249x; 1.3699x over previous
//
#include <hip/hip_runtime.h>

#define DEVFN __device__ __forceinline__

constexpr int B = 4, S = 2048, H = 4, DH = 16, D = 64, F = 256;
constexpr int T = B * S;        // 8192 tokens
constexpr int PAIRS = B * H;    // 16
constexpr int CPP = 72;         // chunk-blocks per pair = sum_{qb=0..15}(qb/2+1)
constexpr int NZ = PAIRS * CPP; // 1152 attention partial blocks
constexpr int PSTRIDE = 1280;   // floats: 128 m + 128 l + 128x16 bf16 acc

typedef __attribute__((ext_vector_type(8))) short s16x8;
typedef __attribute__((ext_vector_type(16))) float f32x16;
typedef unsigned short ushort_t;

DEVFN float wave_sum(float v) {
#pragma unroll
    for (int mask = 32; mask >= 1; mask >>= 1)
        v += __shfl_xor(v, mask, 64);
    return v;
}

DEVFN float bf2f(unsigned short u) { return __uint_as_float((unsigned)u << 16); }
DEVFN unsigned short f2bf(float f) {
    unsigned b = __float_as_uint(f);
    return (unsigned short)((b + 0x8000u) >> 16);
}
DEVFN unsigned pack_bf2(float lo, float hi) {
    unsigned a = __float_as_uint(lo), b = __float_as_uint(hi);
    return ((a + 0x8000u) >> 16) | ((b + 0x8000u) & 0xffff0000u);
}

// ---------------------------------------------------------------- kernel 1
// QKV projection, 8 tokens per block. Outputs bf16: Qb (x0.25 folded),
// Kb [pair][S][16], and V TRANSPOSED Vtg [pair][16][S].
__global__ __launch_bounds__(128) void k_qkv(
    const float* __restrict__ x,
    const float* __restrict__ wq, const float* __restrict__ bq,
    const float* __restrict__ wk, const float* __restrict__ bk,
    const float* __restrict__ wv, const float* __restrict__ bv,
    unsigned short* __restrict__ Qb, unsigned short* __restrict__ Kb,
    unsigned short* __restrict__ Vtg)
{
    __shared__ float xs[8][64];
    int tid = threadIdx.x;
    int t0 = blockIdx.x * 8;
    ((float4*)xs)[tid] = ((const float4*)(x + t0 * D))[tid];
    __syncthreads();

    int j = tid & 63, g = tid >> 6;
    int h = j >> 4, k = j & 15;
    int wbase = h * (D * DH) + k;

    float qa[4], ka[4], va[4];
#pragma unroll
    for (int i = 0; i < 4; ++i) { qa[i] = bq[j]; ka[i] = bk[j]; va[i] = bv[j]; }

#pragma unroll 8
    for (int d = 0; d < D; ++d) {
        float wqv = wq[wbase + d * DH];
        float wkv = wk[wbase + d * DH];
        float wvv = wv[wbase + d * DH];
#pragma unroll
        for (int i = 0; i < 4; ++i) {
            float xd = xs[g * 4 + i][d];
            qa[i] = fmaf(xd, wqv, qa[i]);
            ka[i] = fmaf(xd, wkv, ka[i]);
            va[i] = fmaf(xd, wvv, va[i]);
        }
    }
    int b = t0 >> 11;
    int pair = b * H + h;
    unsigned short vv[4];
#pragma unroll
    for (int i = 0; i < 4; ++i) {
        int t = t0 + g * 4 + i;
        int s = t & (S - 1);
        int off = (pair * S + s) * DH + k;
        Qb[off] = f2bf(qa[i] * 0.25f);
        Kb[off] = f2bf(ka[i]);
        vv[i] = f2bf(va[i]);
    }
    int s0 = (t0 & (S - 1)) + g * 4;
    ushort4 pk = { vv[0], vv[1], vv[2], vv[3] };
    *(ushort4*)(Vtg + (size_t)(pair * DH + k) * S + s0) = pk;
}

// ---------------------------------------------------------------- kernel 2a
// MFMA flash attention partial. Block z -> (pair, qb, kc): 128 q-rows
// [qb*128,+128), 256 keys [kc*256,+256). 4 waves each own 32 q rows.
// S^T = mfma_32x32x16(K, Q^T): lane holds 16 keys for ONE q (n=lane&31)
// -> in-lane softmax, lane-local rescale. PV: O^T = mfma(V^T, P^T).
__global__ __launch_bounds__(256) void k_attn_part(
    const unsigned short* __restrict__ Qb, const unsigned short* __restrict__ Kb,
    const unsigned short* __restrict__ Vtg, float* __restrict__ P)
{
    __shared__ unsigned short Kt[256][16];   // chunk16 slot ^= key&1
    __shared__ unsigned short Vt[16][264];   // padded rows
    __shared__ unsigned short Pt[4][32][32]; // per-wave, b128-slot ^= (q>>1)&3

    int tid = threadIdx.x, lane = tid & 63, w = tid >> 6;

    int z = blockIdx.x;
    int pair = z / CPP;
    int rem = z - pair * CPP;
    int qb = 0, cum = 0;
    while (cum + (qb >> 1) + 1 <= rem) { cum += (qb >> 1) + 1; ++qb; }
    int kc = rem - cum;
    int kbase = kc << 8;
    int qbase = qb << 7;

    // ---- stage K (swizzled) and V^T (padded)
    {
        const uint4* src = (const uint4*)(Kb + (size_t)(pair * S + kbase + tid) * DH);
        uint4 lo = src[0], hi = src[1];
        *(uint4*)&Kt[tid][(tid & 1) * 8] = lo;
        *(uint4*)&Kt[tid][((tid & 1) ^ 1) * 8] = hi;
        int r = tid >> 4, cc = tid & 15;
        const uint4* vs = (const uint4*)(Vtg + (size_t)(pair * DH + r) * S + kbase + cc * 16);
        uint4 v0 = vs[0], v1 = vs[1];
        *(uint4*)&Vt[r][cc * 16] = v0;
        *(uint4*)&Vt[r][cc * 16 + 8] = v1;
    }
    __syncthreads();

    int qn = lane & 31, g = lane >> 5;
    int q0w = qbase + w * 32;
    int qg = q0w + qn;
    int swz = (qn >> 1) & 3;

    s16x8 qf = *(const s16x8*)(Qb + (size_t)(pair * S + qg) * DH + g * 8);

    f32x16 czero;
#pragma unroll
    for (int i = 0; i < 16; ++i) czero[i] = 0.f;
    f32x16 acc = czero;
    float mrun = -1e30f, lsum = 0.f;

    int nt = ((q0w + 31 - kbase) >> 5) + 1;
    if (nt > 8) nt = 8;

    for (int t = 0; t < nt; ++t) {
        int kl = t * 32;
        int krow = kl + qn;
        s16x8 kf = *(const s16x8*)&Kt[krow][(g ^ (krow & 1)) * 8];
        f32x16 sc = __builtin_amdgcn_mfma_f32_32x32x16_bf16(kf, qf, czero, 0, 0, 0);
        if (t == nt - 1) {                       // diagonal tile: causal mask
            int qml = qg - (kbase + kl);
#pragma unroll
            for (int r = 0; r < 16; ++r) {
                int m = (r & 3) + 8 * (r >> 2) + 4 * g;
                sc[r] = (m <= qml) ? sc[r] : -1e30f;
            }
        }
        float tm = sc[0];
#pragma unroll
        for (int r = 1; r < 16; ++r) tm = fmaxf(tm, sc[r]);
        tm = fmaxf(tm, __shfl_xor(tm, 32, 64));
        float mnew = fmaxf(mrun, tm);
        float scale = __expf(mrun - mnew);
        mrun = mnew;
        float p[16];
        float ts = 0.f;
#pragma unroll
        for (int r = 0; r < 16; ++r) { p[r] = __expf(sc[r] - mnew); ts += p[r]; }
        ts += __shfl_xor(ts, 32, 64);
        lsum = fmaf(lsum, scale, ts);
#pragma unroll
        for (int r = 0; r < 8; ++r) acc[r] *= scale;
        // pack P (bf16) into per-wave LDS tile, swizzled b64 writes
#pragma unroll
        for (int c = 0; c < 4; ++c) {
            uint2 dw;
            dw.x = pack_bf2(p[4 * c], p[4 * c + 1]);
            dw.y = pack_bf2(p[4 * c + 2], p[4 * c + 3]);
            *(uint2*)&Pt[w][qn][((c ^ swz) * 8) + g * 4] = dw;
        }
        // PV: O^T += V^T * P^T  (two K=16 halves)
#pragma unroll
        for (int kh = 0; kh < 2; ++kh) {
            s16x8 vf = *(const s16x8*)&Vt[lane & 15][kl + kh * 16 + g * 8];
            s16x8 pf = *(const s16x8*)&Pt[w][qn][((2 * kh + g) ^ swz) * 8];
            acc = __builtin_amdgcn_mfma_f32_32x32x16_bf16(vf, pf, acc, 0, 0, 0);
        }
    }

    // ---- write partial: m/l fp32 per q, acc bf16 [128 q][16 dh]
    float* base = P + (size_t)z * PSTRIDE;
    if (lane < 32) {
        base[w * 32 + qn] = mrun;
        base[128 + w * 32 + qn] = lsum;
    }
    uint2 cA, cB;
    cA.x = pack_bf2(acc[0], acc[1]); cA.y = pack_bf2(acc[2], acc[3]);
    cB.x = pack_bf2(acc[4], acc[5]); cB.y = pack_bf2(acc[6], acc[7]);
    unsigned short* pa = (unsigned short*)(base + 256);
    *(uint2*)&pa[(w * 32 + qn) * 16 + 4 * g] = cA;
    *(uint2*)&pa[(w * 32 + qn) * 16 + 8 + 4 * g] = cB;
}

// ---------------------------------------------------------------- kernel 2b
// Merge the (qb/2+1) key-chunk partials per 128-row group, write A fp32.
__global__ __launch_bounds__(128) void k_attn_merge(
    const float* __restrict__ P, float* __restrict__ A)
{
    int q = threadIdx.x;
    int y = blockIdx.x;
    int pair = y >> 4, qb = y & 15;
    int cum = 0;
#pragma unroll
    for (int i = 0; i < 16; ++i) cum += (i < qb) ? ((i >> 1) + 1) : 0;
    int nc = (qb >> 1) + 1;
    const float* base = P + ((size_t)pair * CPP + cum) * PSTRIDE;

    float M = base[q], Sm = base[128 + q];
    float acc[16];
    {
        const unsigned short* pa = (const unsigned short*)(base + 256);
        uint4 u0 = *(const uint4*)&pa[q * 16];
        uint4 u1 = *(const uint4*)&pa[q * 16 + 8];
        unsigned uu[8] = { u0.x, u0.y, u0.z, u0.w, u1.x, u1.y, u1.z, u1.w };
#pragma unroll
        for (int d = 0; d < 8; ++d) {
            acc[2 * d]     = __uint_as_float(uu[d] << 16);
            acc[2 * d + 1] = __uint_as_float(uu[d] & 0xffff0000u);
        }
    }
    for (int c = 1; c < nc; ++c) {
        base += PSTRIDE;
        float m2 = base[q], s2 = base[128 + q];
        float Mn = fmaxf(M, m2);
        float e1 = __expf(M - Mn), e2 = __expf(m2 - Mn);
        Sm = Sm * e1 + s2 * e2;
        const unsigned short* pa = (const unsigned short*)(base + 256);
        uint4 u0 = *(const uint4*)&pa[q * 16];
        uint4 u1 = *(const uint4*)&pa[q * 16 + 8];
        unsigned uu[8] = { u0.x, u0.y, u0.z, u0.w, u1.x, u1.y, u1.z, u1.w };
#pragma unroll
        for (int d = 0; d < 8; ++d) {
            acc[2 * d]     = acc[2 * d]     * e1 + __uint_as_float(uu[d] << 16) * e2;
            acc[2 * d + 1] = acc[2 * d + 1] * e1 + __uint_as_float(uu[d] & 0xffff0000u) * e2;
        }
        M = Mn;
    }
    float inv = 1.f / Sm;
    int b = pair >> 2, h = pair & 3;
    int row = qb * 128 + q;
    float4* Ap = (float4*)(A + (size_t)(b * S + row) * D + h * DH);
    float4 o0 = { acc[0] * inv,  acc[1] * inv,  acc[2] * inv,  acc[3] * inv };
    float4 o1 = { acc[4] * inv,  acc[5] * inv,  acc[6] * inv,  acc[7] * inv };
    float4 o2 = { acc[8] * inv,  acc[9] * inv,  acc[10] * inv, acc[11] * inv };
    float4 o3 = { acc[12] * inv, acc[13] * inv, acc[14] * inv, acc[15] * inv };
    Ap[0] = o0; Ap[1] = o1; Ap[2] = o2; Ap[3] = o3;
}

// ---------------------------------------------------------------- kernel 3
// Out-projection + residual + LayerNorm1, 8 tokens per block.
__global__ __launch_bounds__(128) void k_oproj(
    const float* __restrict__ A, const float* __restrict__ x,
    const float* __restrict__ wo, const float* __restrict__ bo,
    const float* __restrict__ g1, const float* __restrict__ bb1,
    float* __restrict__ R1)
{
    __shared__ float as[8][64];
    int tid = threadIdx.x;
    int t0 = blockIdx.x * 8;
    ((float4*)as)[tid] = ((const float4*)(A + t0 * D))[tid];
    __syncthreads();

    int j = tid & 63, g = tid >> 6;
    float o[4];
#pragma unroll
    for (int i = 0; i < 4; ++i)
        o[i] = bo[j] + x[(t0 + g * 4 + i) * D + j];

#pragma unroll 8
    for (int d = 0; d < D; ++d) {
        float wv = wo[d * D + j];
#pragma unroll
        for (int i = 0; i < 4; ++i)
            o[i] = fmaf(as[g * 4 + i][d], wv, o[i]);
    }
    float gj = g1[j], bj = bb1[j];
#pragma unroll
    for (int i = 0; i < 4; ++i) {
        float mu  = wave_sum(o[i]) * (1.f / 64.f);
        float dif = o[i] - mu;
        float var = wave_sum(dif * dif) * (1.f / 64.f);
        R1[(t0 + g * 4 + i) * D + j] = dif * rsqrtf(var + 1e-5f) * gj + bj;
    }
}

// ---------------------------------------------------------------- kernel 4
// FFN + residual + LayerNorm2, 16 tokens per block, 512 threads.
__global__ __launch_bounds__(512) void k_ffn(
    const float* __restrict__ R1,
    const float* __restrict__ w1, const float* __restrict__ b1,
    const float* __restrict__ w2, const float* __restrict__ b2,
    const float* __restrict__ g2, const float* __restrict__ bb2,
    float* __restrict__ out)
{
    __shared__ float xr[16][64];
    __shared__ float hh[256][20];
    int tid = threadIdx.x;
    int t0 = blockIdx.x * 16;
    if (tid < 256)
        ((float4*)xr)[tid] = ((const float4*)(R1 + t0 * D))[tid];
    __syncthreads();

    int f = tid & 255, half = tid >> 8;
    float h[8];
#pragma unroll
    for (int t = 0; t < 8; ++t) h[t] = b1[f];
#pragma unroll 8
    for (int d = 0; d < D; ++d) {
        float wv = w1[d * F + f];
#pragma unroll
        for (int t = 0; t < 8; ++t)
            h[t] = fmaf(xr[half * 8 + t][d], wv, h[t]);
    }
#pragma unroll
    for (int t = 0; t < 8; t += 4) {
        float4 hv = { fmaxf(h[t], 0.f), fmaxf(h[t+1], 0.f),
                      fmaxf(h[t+2], 0.f), fmaxf(h[t+3], 0.f) };
        *(float4*)&hh[f][half * 8 + t] = hv;
    }
    __syncthreads();

    int j = tid & 63, g = tid >> 6;
    float y0 = b2[j] + xr[2 * g + 0][j];
    float y1 = b2[j] + xr[2 * g + 1][j];
#pragma unroll 8
    for (int ff = 0; ff < F; ++ff) {
        float wv = w2[ff * D + j];
        float2 hv = *(const float2*)&hh[ff][2 * g];
        y0 = fmaf(hv.x, wv, y0);
        y1 = fmaf(hv.y, wv, y1);
    }
    float gj = g2[j], bj = bb2[j];
    {
        float mu  = wave_sum(y0) * (1.f / 64.f);
        float dif = y0 - mu;
        float var = wave_sum(dif * dif) * (1.f / 64.f);
        out[(t0 + 2 * g + 0) * D + j] = dif * rsqrtf(var + 1e-5f) * gj + bj;
    }
    {
        float mu  = wave_sum(y1) * (1.f / 64.f);
        float dif = y1 - mu;
        float var = wave_sum(dif * dif) * (1.f / 64.f);
        out[(t0 + 2 * g + 1) * D + j] = dif * rsqrtf(var + 1e-5f) * gj + bj;
    }
}

// ----------------------------------------------------------------
extern "C" void kernel_launch(void* const* d_in, const int* in_sizes, int n_in,
                              void* d_out, int out_size, void* d_ws, size_t ws_size,
                              hipStream_t stream)
{
    const float* x   = (const float*)d_in[0];
    const float* wq  = (const float*)d_in[1];
    const float* bq  = (const float*)d_in[2];
    const float* wk  = (const float*)d_in[3];
    const float* bk  = (const float*)d_in[4];
    const float* wv  = (const float*)d_in[5];
    const float* bv  = (const float*)d_in[6];
    const float* wo  = (const float*)d_in[7];
    const float* bo  = (const float*)d_in[8];
    const float* g1  = (const float*)d_in[9];
    const float* be1 = (const float*)d_in[10];
    const float* w1  = (const float*)d_in[11];
    const float* b1  = (const float*)d_in[12];
    const float* w2  = (const float*)d_in[13];
    const float* b2  = (const float*)d_in[14];
    const float* g2  = (const float*)d_in[15];
    const float* be2 = (const float*)d_in[16];

    char* base = (char*)d_ws;
    unsigned short* Qb  = (unsigned short*)base;                  // 1 MB
    unsigned short* Kb  = (unsigned short*)(base + (1u << 20));   // 1 MB
    unsigned short* Vtg = (unsigned short*)(base + (2u << 20));   // 1 MB
    float*          A   = (float*)(base + (3u << 20));            // 2 MB
    float*          R1  = (float*)(base + (5u << 20));            // 2 MB
    float*          P   = (float*)(base + (7u << 20));            // 5.9 MB

    k_qkv       <<<T / 8, 128, 0, stream>>>(x, wq, bq, wk, bk, wv, bv, Qb, Kb, Vtg);
    k_attn_part <<<NZ, 256, 0, stream>>>(Qb, Kb, Vtg, P);
    k_attn_merge<<<PAIRS * 16, 128, 0, stream>>>(P, A);
    k_oproj     <<<T / 8, 128, 0, stream>>>(A, x, wo, bo, g1, be1, R1);
    k_ffn       <<<T / 16, 512, 0, stream>>>(R1, w1, b1, w2, b2, g2, be2, (float*)d_out);
}

// Round 7
// 68.657 us; speedup vs baseline: 2.6853x; 1.1074x over previous
//
#include <hip/hip_runtime.h>

#define DEVFN __device__ __forceinline__

constexpr int B = 4, S = 2048, H = 4, DH = 16, D = 64, F = 256;
constexpr int T = B * S;        // 8192 tokens
constexpr int PAIRS = B * H;    // 16
constexpr int CPP = 72;         // chunk-blocks per pair = sum_{qb=0..15}(qb/2+1)
constexpr int NZ = PAIRS * CPP; // 1152 attention partial blocks
constexpr int PSTRIDE = 1280;   // floats: 128 m + 128 l + 128x16 bf16 acc

typedef __attribute__((ext_vector_type(8))) short s16x8;
typedef __attribute__((ext_vector_type(16))) float f32x16;

DEVFN float wave_sum(float v) {
#pragma unroll
    for (int mask = 32; mask >= 1; mask >>= 1)
        v += __shfl_xor(v, mask, 64);
    return v;
}

DEVFN float bf2f(unsigned short u) { return __uint_as_float((unsigned)u << 16); }
DEVFN unsigned short f2bf(float f) {
    unsigned b = __float_as_uint(f);
    return (unsigned short)((b + 0x8000u) >> 16);
}
DEVFN unsigned pack_bf2(float lo, float hi) {
    unsigned a = __float_as_uint(lo), b = __float_as_uint(hi);
    return ((a + 0x8000u) >> 16) | ((b + 0x8000u) & 0xffff0000u);
}

// ---------------------------------------------------------------- kernel 1
// QKV projection, 8 tokens per block. Outputs bf16: Qb (x0.25 folded),
// Kb [pair][S][16], and V TRANSPOSED Vtg [pair][16][S].
__global__ __launch_bounds__(128) void k_qkv(
    const float* __restrict__ x,
    const float* __restrict__ wq, const float* __restrict__ bq,
    const float* __restrict__ wk, const float* __restrict__ bk,
    const float* __restrict__ wv, const float* __restrict__ bv,
    unsigned short* __restrict__ Qb, unsigned short* __restrict__ Kb,
    unsigned short* __restrict__ Vtg)
{
    __shared__ float xs[8][64];
    int tid = threadIdx.x;
    int t0 = blockIdx.x * 8;
    ((float4*)xs)[tid] = ((const float4*)(x + t0 * D))[tid];
    __syncthreads();

    int j = tid & 63, g = tid >> 6;
    int h = j >> 4, k = j & 15;
    int wbase = h * (D * DH) + k;

    float qa[4], ka[4], va[4];
#pragma unroll
    for (int i = 0; i < 4; ++i) { qa[i] = bq[j]; ka[i] = bk[j]; va[i] = bv[j]; }

#pragma unroll 8
    for (int d = 0; d < D; ++d) {
        float wqv = wq[wbase + d * DH];
        float wkv = wk[wbase + d * DH];
        float wvv = wv[wbase + d * DH];
#pragma unroll
        for (int i = 0; i < 4; ++i) {
            float xd = xs[g * 4 + i][d];
            qa[i] = fmaf(xd, wqv, qa[i]);
            ka[i] = fmaf(xd, wkv, ka[i]);
            va[i] = fmaf(xd, wvv, va[i]);
        }
    }
    int b = t0 >> 11;
    int pair = b * H + h;
    unsigned short vv[4];
#pragma unroll
    for (int i = 0; i < 4; ++i) {
        int t = t0 + g * 4 + i;
        int s = t & (S - 1);
        int off = (pair * S + s) * DH + k;
        Qb[off] = f2bf(qa[i] * 0.25f);
        Kb[off] = f2bf(ka[i]);
        vv[i] = f2bf(va[i]);
    }
    int s0 = (t0 & (S - 1)) + g * 4;
    ushort4 pk = { vv[0], vv[1], vv[2], vv[3] };
    *(ushort4*)(Vtg + (size_t)(pair * DH + k) * S + s0) = pk;
}

// ---------------------------------------------------------------- kernel 2
// MFMA flash attention partial (unchanged from R6).
__global__ __launch_bounds__(256) void k_attn_part(
    const unsigned short* __restrict__ Qb, const unsigned short* __restrict__ Kb,
    const unsigned short* __restrict__ Vtg, float* __restrict__ P)
{
    __shared__ unsigned short Kt[256][16];   // chunk16 slot ^= key&1
    __shared__ unsigned short Vt[16][264];   // padded rows
    __shared__ unsigned short Pt[4][32][32]; // per-wave, b128-slot ^= (q>>1)&3

    int tid = threadIdx.x, lane = tid & 63, w = tid >> 6;

    int z = blockIdx.x;
    int pair = z / CPP;
    int rem = z - pair * CPP;
    int qb = 0, cum = 0;
    while (cum + (qb >> 1) + 1 <= rem) { cum += (qb >> 1) + 1; ++qb; }
    int kc = rem - cum;
    int kbase = kc << 8;
    int qbase = qb << 7;

    {
        const uint4* src = (const uint4*)(Kb + (size_t)(pair * S + kbase + tid) * DH);
        uint4 lo = src[0], hi = src[1];
        *(uint4*)&Kt[tid][(tid & 1) * 8] = lo;
        *(uint4*)&Kt[tid][((tid & 1) ^ 1) * 8] = hi;
        int r = tid >> 4, cc = tid & 15;
        const uint4* vs = (const uint4*)(Vtg + (size_t)(pair * DH + r) * S + kbase + cc * 16);
        uint4 v0 = vs[0], v1 = vs[1];
        *(uint4*)&Vt[r][cc * 16] = v0;
        *(uint4*)&Vt[r][cc * 16 + 8] = v1;
    }
    __syncthreads();

    int qn = lane & 31, g = lane >> 5;
    int q0w = qbase + w * 32;
    int qg = q0w + qn;
    int swz = (qn >> 1) & 3;

    s16x8 qf = *(const s16x8*)(Qb + (size_t)(pair * S + qg) * DH + g * 8);

    f32x16 czero;
#pragma unroll
    for (int i = 0; i < 16; ++i) czero[i] = 0.f;
    f32x16 acc = czero;
    float mrun = -1e30f, lsum = 0.f;

    int nt = ((q0w + 31 - kbase) >> 5) + 1;
    if (nt > 8) nt = 8;

    for (int t = 0; t < nt; ++t) {
        int kl = t * 32;
        int krow = kl + qn;
        s16x8 kf = *(const s16x8*)&Kt[krow][(g ^ (krow & 1)) * 8];
        f32x16 sc = __builtin_amdgcn_mfma_f32_32x32x16_bf16(kf, qf, czero, 0, 0, 0);
        if (t == nt - 1) {
            int qml = qg - (kbase + kl);
#pragma unroll
            for (int r = 0; r < 16; ++r) {
                int m = (r & 3) + 8 * (r >> 2) + 4 * g;
                sc[r] = (m <= qml) ? sc[r] : -1e30f;
            }
        }
        float tm = sc[0];
#pragma unroll
        for (int r = 1; r < 16; ++r) tm = fmaxf(tm, sc[r]);
        tm = fmaxf(tm, __shfl_xor(tm, 32, 64));
        float mnew = fmaxf(mrun, tm);
        float scale = __expf(mrun - mnew);
        mrun = mnew;
        float p[16];
        float ts = 0.f;
#pragma unroll
        for (int r = 0; r < 16; ++r) { p[r] = __expf(sc[r] - mnew); ts += p[r]; }
        ts += __shfl_xor(ts, 32, 64);
        lsum = fmaf(lsum, scale, ts);
#pragma unroll
        for (int r = 0; r < 8; ++r) acc[r] *= scale;
#pragma unroll
        for (int c = 0; c < 4; ++c) {
            uint2 dw;
            dw.x = pack_bf2(p[4 * c], p[4 * c + 1]);
            dw.y = pack_bf2(p[4 * c + 2], p[4 * c + 3]);
            *(uint2*)&Pt[w][qn][((c ^ swz) * 8) + g * 4] = dw;
        }
#pragma unroll
        for (int kh = 0; kh < 2; ++kh) {
            s16x8 vf = *(const s16x8*)&Vt[lane & 15][kl + kh * 16 + g * 8];
            s16x8 pf = *(const s16x8*)&Pt[w][qn][((2 * kh + g) ^ swz) * 8];
            acc = __builtin_amdgcn_mfma_f32_32x32x16_bf16(vf, pf, acc, 0, 0, 0);
        }
    }

    float* base = P + (size_t)z * PSTRIDE;
    if (lane < 32) {
        base[w * 32 + qn] = mrun;
        base[128 + w * 32 + qn] = lsum;
    }
    uint2 cA, cB;
    cA.x = pack_bf2(acc[0], acc[1]); cA.y = pack_bf2(acc[2], acc[3]);
    cB.x = pack_bf2(acc[4], acc[5]); cB.y = pack_bf2(acc[6], acc[7]);
    unsigned short* pa = (unsigned short*)(base + 256);
    *(uint2*)&pa[(w * 32 + qn) * 16 + 4 * g] = cA;
    *(uint2*)&pa[(w * 32 + qn) * 16 + 8 + 4 * g] = cB;
}

// ---------------------------------------------------------------- kernel 3
// Fused: attn-merge + out-proj + residual + LN1 + FFN + residual + LN2.
// 16 tokens per block, 512 threads. A and R1 live only in LDS.
__global__ __launch_bounds__(512) void k_post(
    const float* __restrict__ P, const float* __restrict__ x,
    const float* __restrict__ wo, const float* __restrict__ bo,
    const float* __restrict__ g1, const float* __restrict__ bb1,
    const float* __restrict__ w1, const float* __restrict__ b1,
    const float* __restrict__ w2, const float* __restrict__ b2,
    const float* __restrict__ g2, const float* __restrict__ bb2,
    float* __restrict__ out)
{
    __shared__ float As[16][68];     // merged attention out (head-concat)
    __shared__ float R1s[16][68];    // post-LN1
    __shared__ float hh[256][20];    // ffn hidden, padded

    int tid = threadIdx.x;
    int t0 = blockIdx.x * 16;
    int b = t0 >> 11;
    int sbase = t0 & (S - 1);
    int qb = sbase >> 7;
    int nc = (qb >> 1) + 1;
    int cum = 0;
#pragma unroll
    for (int i = 0; i < 16; ++i) cum += (i < qb) ? ((i >> 1) + 1) : 0;

    // ---- phase 1: merge split-K partials -> As
    {
        int pi = tid >> 3;           // 0..63 = (h, sl)
        int h = pi >> 4, sl = pi & 15;
        int dq = tid & 7;            // dims 2dq, 2dq+1
        int pair = b * H + h;
        int q = (sbase & 127) + sl;
        const float* base = P + ((size_t)pair * CPP + cum) * PSTRIDE;

        float M = base[q], Sm = base[128 + q];
        unsigned u = *(const unsigned*)((const unsigned short*)(base + 256) + q * 16 + dq * 2);
        float a0 = __uint_as_float(u << 16);
        float a1 = __uint_as_float(u & 0xffff0000u);
        for (int c = 1; c < nc; ++c) {
            base += PSTRIDE;
            float m2 = base[q], s2 = base[128 + q];
            float Mn = fmaxf(M, m2);
            float e1 = __expf(M - Mn), e2 = __expf(m2 - Mn);
            Sm = Sm * e1 + s2 * e2;
            unsigned u2 = *(const unsigned*)((const unsigned short*)(base + 256) + q * 16 + dq * 2);
            a0 = a0 * e1 + __uint_as_float(u2 << 16) * e2;
            a1 = a1 * e1 + __uint_as_float(u2 & 0xffff0000u) * e2;
            M = Mn;
        }
        float inv = 1.f / Sm;
        float2 wv = { a0 * inv, a1 * inv };
        *(float2*)&As[sl][h * 16 + dq * 2] = wv;
    }
    __syncthreads();

    // ---- phase 2: out-proj + residual + LN1 -> R1s
    {
        int g = tid >> 6, j = tid & 63;      // tokens 2g, 2g+1
        float o0 = bo[j] + x[(t0 + 2 * g + 0) * D + j];
        float o1 = bo[j] + x[(t0 + 2 * g + 1) * D + j];
#pragma unroll
        for (int d4 = 0; d4 < 16; ++d4) {
            float w0 = wo[(4 * d4 + 0) * D + j];
            float w1v = wo[(4 * d4 + 1) * D + j];
            float w2v = wo[(4 * d4 + 2) * D + j];
            float w3v = wo[(4 * d4 + 3) * D + j];
            float4 av0 = *(const float4*)&As[2 * g + 0][d4 * 4];
            float4 av1 = *(const float4*)&As[2 * g + 1][d4 * 4];
            o0 = fmaf(av0.x, w0, o0); o0 = fmaf(av0.y, w1v, o0);
            o0 = fmaf(av0.z, w2v, o0); o0 = fmaf(av0.w, w3v, o0);
            o1 = fmaf(av1.x, w0, o1); o1 = fmaf(av1.y, w1v, o1);
            o1 = fmaf(av1.z, w2v, o1); o1 = fmaf(av1.w, w3v, o1);
        }
        float gj = g1[j], bj = bb1[j];
        {
            float mu = wave_sum(o0) * (1.f / 64.f);
            float dif = o0 - mu;
            float var = wave_sum(dif * dif) * (1.f / 64.f);
            R1s[2 * g + 0][j] = dif * rsqrtf(var + 1e-5f) * gj + bj;
        }
        {
            float mu = wave_sum(o1) * (1.f / 64.f);
            float dif = o1 - mu;
            float var = wave_sum(dif * dif) * (1.f / 64.f);
            R1s[2 * g + 1][j] = dif * rsqrtf(var + 1e-5f) * gj + bj;
        }
    }
    __syncthreads();

    // ---- phase 3: FFN stage 1 (hidden) -> hh
    {
        int f = tid & 255, half = tid >> 8;
        float h[8];
#pragma unroll
        for (int t = 0; t < 8; ++t) h[t] = b1[f];
#pragma unroll
        for (int d4 = 0; d4 < 16; ++d4) {
            float w0 = w1[(4 * d4 + 0) * F + f];
            float w1v = w1[(4 * d4 + 1) * F + f];
            float w2v = w1[(4 * d4 + 2) * F + f];
            float w3v = w1[(4 * d4 + 3) * F + f];
#pragma unroll
            for (int t = 0; t < 8; ++t) {
                float4 xv = *(const float4*)&R1s[half * 8 + t][d4 * 4];
                h[t] = fmaf(xv.x, w0, h[t]); h[t] = fmaf(xv.y, w1v, h[t]);
                h[t] = fmaf(xv.z, w2v, h[t]); h[t] = fmaf(xv.w, w3v, h[t]);
            }
        }
#pragma unroll
        for (int t = 0; t < 8; t += 4) {
            float4 hv = { fmaxf(h[t], 0.f), fmaxf(h[t+1], 0.f),
                          fmaxf(h[t+2], 0.f), fmaxf(h[t+3], 0.f) };
            *(float4*)&hh[f][half * 8 + t] = hv;
        }
    }
    __syncthreads();

    // ---- phase 4: FFN stage 2 + residual + LN2 -> out
    {
        int g = tid >> 6, j = tid & 63;
        float y0 = b2[j] + R1s[2 * g + 0][j];
        float y1 = b2[j] + R1s[2 * g + 1][j];
#pragma unroll 8
        for (int ff = 0; ff < F; ++ff) {
            float wv = w2[ff * D + j];
            float2 hv = *(const float2*)&hh[ff][2 * g];
            y0 = fmaf(hv.x, wv, y0);
            y1 = fmaf(hv.y, wv, y1);
        }
        float gj = g2[j], bj = bb2[j];
        {
            float mu = wave_sum(y0) * (1.f / 64.f);
            float dif = y0 - mu;
            float var = wave_sum(dif * dif) * (1.f / 64.f);
            out[(t0 + 2 * g + 0) * D + j] = dif * rsqrtf(var + 1e-5f) * gj + bj;
        }
        {
            float mu = wave_sum(y1) * (1.f / 64.f);
            float dif = y1 - mu;
            float var = wave_sum(dif * dif) * (1.f / 64.f);
            out[(t0 + 2 * g + 1) * D + j] = dif * rsqrtf(var + 1e-5f) * gj + bj;
        }
    }
}

// ----------------------------------------------------------------
extern "C" void kernel_launch(void* const* d_in, const int* in_sizes, int n_in,
                              void* d_out, int out_size, void* d_ws, size_t ws_size,
                              hipStream_t stream)
{
    const float* x   = (const float*)d_in[0];
    const float* wq  = (const float*)d_in[1];
    const float* bq  = (const float*)d_in[2];
    const float* wk  = (const float*)d_in[3];
    const float* bk  = (const float*)d_in[4];
    const float* wv  = (const float*)d_in[5];
    const float* bv  = (const float*)d_in[6];
    const float* wo  = (const float*)d_in[7];
    const float* bo  = (const float*)d_in[8];
    const float* g1  = (const float*)d_in[9];
    const float* be1 = (const float*)d_in[10];
    const float* w1  = (const float*)d_in[11];
    const float* b1  = (const float*)d_in[12];
    const float* w2  = (const float*)d_in[13];
    const float* b2  = (const float*)d_in[14];
    const float* g2  = (const float*)d_in[15];
    const float* be2 = (const float*)d_in[16];

    char* base = (char*)d_ws;
    unsigned short* Qb  = (unsigned short*)base;                  // 1 MB
    unsigned short* Kb  = (unsigned short*)(base + (1u << 20));   // 1 MB
    unsigned short* Vtg = (unsigned short*)(base + (2u << 20));   // 1 MB
    float*          P   = (float*)(base + (3u << 20));            // 5.9 MB

    k_qkv      <<<T / 8, 128, 0, stream>>>(x, wq, bq, wk, bk, wv, bv, Qb, Kb, Vtg);
    k_attn_part<<<NZ, 256, 0, stream>>>(Qb, Kb, Vtg, P);
    k_post     <<<T / 16, 512, 0, stream>>>(P, x, wo, bo, g1, be1,
                                            w1, b1, w2, b2, g2, be2,
                                            (float*)d_out);
}